// Round 7
// baseline (349.359 us; speedup 1.0000x reference)
//
#include <hip/hip_runtime.h>

#define N_NODES 50000
#define E_EDGES 800000
#define SCAN_NBLK 196   // ceil(50000/256)

// ---------------- CSR build ----------------

__global__ void k_count(const int* __restrict__ dst, int* __restrict__ cnt) {
    int e = blockIdx.x * blockDim.x + threadIdx.x;
    if (e < E_EDGES) atomicAdd(&cnt[dst[e]], 1);
}

// phase A: per-block exclusive scan of cnt -> excl (in-place ok), block sums -> bsum
__global__ void k_scan_part(const int* __restrict__ cnt, int* __restrict__ excl,
                            int* __restrict__ bsum) {
    __shared__ int sm[256];
    int b = blockIdx.x, t = threadIdx.x;
    int i = b * 256 + t;
    int v = (i < N_NODES) ? cnt[i] : 0;
    sm[t] = v;
    __syncthreads();
    for (int off = 1; off < 256; off <<= 1) {
        int u = (t >= off) ? sm[t - off] : 0;
        __syncthreads();
        sm[t] += u;
        __syncthreads();
    }
    if (i < N_NODES) excl[i] = sm[t] - v;
    if (t == 255) bsum[b] = sm[255];
}

// phase B: exclusive scan of the block sums (SCAN_NBLK <= 256)
__global__ void k_scan_bsum(const int* __restrict__ bsum, int* __restrict__ boff) {
    __shared__ int sm[256];
    int t = threadIdx.x;
    int v = (t < SCAN_NBLK) ? bsum[t] : 0;
    sm[t] = v;
    __syncthreads();
    for (int off = 1; off < 256; off <<= 1) {
        int u = (t >= off) ? sm[t - off] : 0;
        __syncthreads();
        sm[t] += u;
        __syncthreads();
    }
    if (t < SCAN_NBLK) boff[t] = sm[t] - v;
}

// phase C: add block offsets, produce rowptr + cursor
__global__ void k_scan_add(int* __restrict__ rowptr, const int* __restrict__ boff,
                           int* __restrict__ cursor) {
    int b = blockIdx.x, t = threadIdx.x;
    int i = b * 256 + t;
    if (i < N_NODES) {
        int r = rowptr[i] + boff[b];
        rowptr[i] = r;
        cursor[i] = r;
    }
    if (i == 0) rowptr[N_NODES] = E_EDGES;
}

__global__ void k_fill(const int* __restrict__ src, const int* __restrict__ dst,
                       int* __restrict__ cursor, int* __restrict__ eidx) {
    int e = blockIdx.x * blockDim.x + threadIdx.x;
    if (e < E_EDGES) {
        int p = atomicAdd(&cursor[dst[e]], 1);
        eidx[p] = src[e];
    }
}

// ---------------- gathers ----------------

// mean[i,o] = (1/max(deg,1)) * sum_{j in N(i)} x[j,o]   (128 threads / node)
__global__ void k_gather128(const int* __restrict__ rowptr, const int* __restrict__ eidx,
                            const float* __restrict__ x, float* __restrict__ mean) {
    int i = blockIdx.x;
    int o = threadIdx.x;
    int beg = rowptr[i], end = rowptr[i + 1];
    float acc = 0.0f;
    int j = beg;
    for (; j + 3 < end; j += 4) {
        int s0 = eidx[j], s1 = eidx[j + 1], s2 = eidx[j + 2], s3 = eidx[j + 3];
        float v0 = x[(size_t)s0 * 128 + o];
        float v1 = x[(size_t)s1 * 128 + o];
        float v2 = x[(size_t)s2 * 128 + o];
        float v3 = x[(size_t)s3 * 128 + o];
        acc += v0 + v1 + v2 + v3;
    }
    for (; j < end; ++j)
        acc += x[(size_t)eidx[j] * 128 + o];
    float inv = 1.0f / fmaxf((float)(end - beg), 1.0f);
    mean[(size_t)i * 128 + o] = acc * inv;
}

// out[i,o] = z[i,80][40+o] + inv * sum_{j in N(i)} z[j,80][o]   (o < 40)
// block = 320 threads = 8 nodes x 40 lanes (grid*8 == N exactly)
__global__ void k_gather40(const int* __restrict__ rowptr, const int* __restrict__ eidx,
                           const float* __restrict__ z, float* __restrict__ out) {
    int t = threadIdx.x;
    int i = blockIdx.x * 8 + t / 40;
    int o = t % 40;
    int beg = rowptr[i], end = rowptr[i + 1];
    float acc = 0.0f;
    int j = beg;
    for (; j + 3 < end; j += 4) {
        int s0 = eidx[j], s1 = eidx[j + 1], s2 = eidx[j + 2], s3 = eidx[j + 3];
        float v0 = z[(size_t)s0 * 80 + o];
        float v1 = z[(size_t)s1 * 80 + o];
        float v2 = z[(size_t)s2 * 80 + o];
        float v3 = z[(size_t)s3 * 80 + o];
        acc += v0 + v1 + v2 + v3;
    }
    for (; j < end; ++j)
        acc += z[(size_t)eidx[j] * 80 + o];
    float inv = 1.0f / fmaxf((float)(end - beg), 1.0f);
    out[(size_t)i * 40 + o] = z[(size_t)i * 80 + 40 + o] + acc * inv;
}

// ---------------- layer 1 dense (scalar-B, no LDS) ----------------
// h[n, c] = relu( sum_k mean[n,k]*W1l[c,k] + sum_k x[n,k]*W1r[c,k] + b1[c] )
// lane = node; wave covers 64 nodes x 16 cols (acc in VGPRs, B via s_load).
// grid = 782 node-blocks x 2 col-halves; block 256 thr = 4 waves.
__launch_bounds__(256)
__global__ void k_dense1_sg(const float* __restrict__ mean, const float* __restrict__ x,
                            const float* __restrict__ W1l, const float* __restrict__ W1r,
                            const float* __restrict__ b1, float* __restrict__ h) {
    int lane = threadIdx.x & 63;
    int wv   = threadIdx.x >> 6;                 // 0..3
    int nblk = blockIdx.x >> 1;
    int cblk = blockIdx.x & 1;
    int c0 = __builtin_amdgcn_readfirstlane(cblk * 64 + wv * 16);
    int n  = nblk * 64 + lane;
    int nc = min(n, N_NODES - 1);

    float acc[16];
#pragma unroll
    for (int q = 0; q < 16; ++q) acc[q] = 0.0f;

#pragma unroll 1
    for (int pass = 0; pass < 2; ++pass) {
        const float* __restrict__ a = (pass == 0) ? (mean + (size_t)nc * 128)
                                                  : (x    + (size_t)nc * 128);
        const float* __restrict__ W = (pass == 0) ? W1l : W1r;

#pragma unroll 2
        for (int kk0 = 0; kk0 < 128; kk0 += 4) {
            float4 av = *(const float4*)(a + kk0);
#pragma unroll
            for (int q = 0; q < 16; ++q) {
                float4 bv = *(const float4*)(W + (size_t)(c0 + q) * 128 + kk0);
                acc[q] = fmaf(av.x, bv.x, acc[q]);
                acc[q] = fmaf(av.y, bv.y, acc[q]);
                acc[q] = fmaf(av.z, bv.z, acc[q]);
                acc[q] = fmaf(av.w, bv.w, acc[q]);
            }
        }
    }

    if (n < N_NODES) {
#pragma unroll
        for (int g = 0; g < 4; ++g) {
            float4 r;
            r.x = fmaxf(acc[g * 4 + 0] + b1[c0 + g * 4 + 0], 0.0f);
            r.y = fmaxf(acc[g * 4 + 1] + b1[c0 + g * 4 + 1], 0.0f);
            r.z = fmaxf(acc[g * 4 + 2] + b1[c0 + g * 4 + 2], 0.0f);
            r.w = fmaxf(acc[g * 4 + 3] + b1[c0 + g * 4 + 3], 0.0f);
            *(float4*)&h[(size_t)n * 128 + c0 + g * 4] = r;
        }
    }
}

// ---------------- layer 2 dense (scalar-B, no LDS) ----------------
// z[n, c] = sum_k h[n,k]*W2l[c,k]            for c in [0,40)
//         = sum_k h[n,k]*W2r[c-40,k] + b2    for c in [40,80)
// lane = node; wave covers 64 nodes x 10 cols. grid = 782 x 2 col-halves.
__launch_bounds__(256)
__global__ void k_dense2_sg(const float* __restrict__ h,
                            const float* __restrict__ W2l, const float* __restrict__ W2r,
                            const float* __restrict__ b2, float* __restrict__ z) {
    int lane = threadIdx.x & 63;
    int wv   = threadIdx.x >> 6;                 // 0..3
    int nblk = blockIdx.x >> 1;
    int cblk = blockIdx.x & 1;                   // 0: W2l cols 0-39, 1: W2r cols 40-79
    int cr0 = __builtin_amdgcn_readfirstlane(wv * 10);   // row in W2l/W2r
    int n  = nblk * 64 + lane;
    int nc = min(n, N_NODES - 1);

    const float* __restrict__ W = (cblk == 0) ? W2l : W2r;
    const float* __restrict__ a = h + (size_t)nc * 128;

    float acc[10];
#pragma unroll
    for (int q = 0; q < 10; ++q) acc[q] = 0.0f;

#pragma unroll 2
    for (int kk0 = 0; kk0 < 128; kk0 += 4) {
        float4 av = *(const float4*)(a + kk0);
#pragma unroll
        for (int q = 0; q < 10; ++q) {
            float4 bv = *(const float4*)(W + (size_t)(cr0 + q) * 128 + kk0);
            acc[q] = fmaf(av.x, bv.x, acc[q]);
            acc[q] = fmaf(av.y, bv.y, acc[q]);
            acc[q] = fmaf(av.z, bv.z, acc[q]);
            acc[q] = fmaf(av.w, bv.w, acc[q]);
        }
    }

    if (n < N_NODES) {
        float bias[10];
#pragma unroll
        for (int q = 0; q < 10; ++q)
            bias[q] = (cblk == 1) ? b2[cr0 + q] : 0.0f;
        size_t base = (size_t)n * 80 + cblk * 40 + cr0;
#pragma unroll
        for (int q = 0; q < 5; ++q) {
            float2 r;
            r.x = acc[2 * q]     + bias[2 * q];
            r.y = acc[2 * q + 1] + bias[2 * q + 1];
            *(float2*)&z[base + 2 * q] = r;
        }
    }
}

// ---------------- launch ----------------

extern "C" void kernel_launch(void* const* d_in, const int* in_sizes, int n_in,
                              void* d_out, int out_size, void* d_ws, size_t ws_size,
                              hipStream_t stream) {
    const float* x   = (const float*)d_in[0];
    const int*   ei  = (const int*)d_in[1];      // [2, E] int32
    const float* W1l = (const float*)d_in[2];
    const float* b1  = (const float*)d_in[3];
    const float* W1r = (const float*)d_in[4];
    const float* W2l = (const float*)d_in[5];
    const float* b2  = (const float*)d_in[6];
    const float* W2r = (const float*)d_in[7];

    const int* src = ei;
    const int* dst = ei + E_EDGES;

    // ---- workspace carve (16B-aligned) ----
    char* base = (char*)d_ws;
    size_t off = 0;
    auto carve = [&](size_t bytes) {
        void* p = base + off;
        off += (bytes + 15) & ~(size_t)15;
        return p;
    };
    int*   cnt    = (int*)  carve((size_t)N_NODES * 4);
    int*   rowptr = (int*)  carve((size_t)(N_NODES + 1) * 4);
    int*   cursor = (int*)  carve((size_t)N_NODES * 4);
    int*   eidx   = (int*)  carve((size_t)E_EDGES * 4);
    int*   bsum   = (int*)  carve((size_t)256 * 4);
    int*   boff   = (int*)  carve((size_t)256 * 4);
    float* mean   = (float*)carve((size_t)N_NODES * 128 * 4);
    float* h      = (float*)carve((size_t)N_NODES * 128 * 4);
    float* z      = mean;   // mean dead after k_dense1_sg; z is N*80 < N*128
    float* outp   = (float*)d_out;

    // ---- CSR build ----
    hipMemsetAsync(cnt, 0, (size_t)N_NODES * 4, stream);
    k_count<<<(E_EDGES + 255) / 256, 256, 0, stream>>>(dst, cnt);
    k_scan_part<<<SCAN_NBLK, 256, 0, stream>>>(cnt, rowptr, bsum);
    k_scan_bsum<<<1, 256, 0, stream>>>(bsum, boff);
    k_scan_add<<<SCAN_NBLK, 256, 0, stream>>>(rowptr, boff, cursor);
    k_fill<<<(E_EDGES + 255) / 256, 256, 0, stream>>>(src, dst, cursor, eidx);

    // ---- layer 1 ----
    k_gather128<<<N_NODES, 128, 0, stream>>>(rowptr, eidx, x, mean);
    {
        int nblocks = ((N_NODES + 63) / 64) * 2;   // 782 node-blocks x 2 col-halves
        k_dense1_sg<<<nblocks, 256, 0, stream>>>(mean, x, W1l, W1r, b1, h);
    }

    // ---- layer 2 ----
    {
        int nblocks = ((N_NODES + 63) / 64) * 2;   // 782 x 2 col-halves (40 cols each)
        k_dense2_sg<<<nblocks, 256, 0, stream>>>(h, W2l, W2r, b2, z);
    }
    k_gather40<<<(N_NODES + 7) / 8, 320, 0, stream>>>(rowptr, eidx, z, outp);
}

// Round 8
// 306.617 us; speedup vs baseline: 1.1394x; 1.1394x over previous
//
#include <hip/hip_runtime.h>

#define N_NODES 50000
#define E_EDGES 800000
#define SCAN_NBLK 196   // ceil(50000/256)

// ---------------- CSR build ----------------

__global__ void k_count(const int* __restrict__ dst, int* __restrict__ cnt) {
    int e = blockIdx.x * blockDim.x + threadIdx.x;
    if (e < E_EDGES) atomicAdd(&cnt[dst[e]], 1);
}

// phase A: per-block exclusive scan of cnt -> excl (in-place ok), block sums -> bsum
__global__ void k_scan_part(const int* __restrict__ cnt, int* __restrict__ excl,
                            int* __restrict__ bsum) {
    __shared__ int sm[256];
    int b = blockIdx.x, t = threadIdx.x;
    int i = b * 256 + t;
    int v = (i < N_NODES) ? cnt[i] : 0;
    sm[t] = v;
    __syncthreads();
    for (int off = 1; off < 256; off <<= 1) {
        int u = (t >= off) ? sm[t - off] : 0;
        __syncthreads();
        sm[t] += u;
        __syncthreads();
    }
    if (i < N_NODES) excl[i] = sm[t] - v;
    if (t == 255) bsum[b] = sm[255];
}

// phase B: exclusive scan of the block sums (SCAN_NBLK <= 256)
__global__ void k_scan_bsum(const int* __restrict__ bsum, int* __restrict__ boff) {
    __shared__ int sm[256];
    int t = threadIdx.x;
    int v = (t < SCAN_NBLK) ? bsum[t] : 0;
    sm[t] = v;
    __syncthreads();
    for (int off = 1; off < 256; off <<= 1) {
        int u = (t >= off) ? sm[t - off] : 0;
        __syncthreads();
        sm[t] += u;
        __syncthreads();
    }
    if (t < SCAN_NBLK) boff[t] = sm[t] - v;
}

// phase C: add block offsets, produce rowptr + cursor
__global__ void k_scan_add(int* __restrict__ rowptr, const int* __restrict__ boff,
                           int* __restrict__ cursor) {
    int b = blockIdx.x, t = threadIdx.x;
    int i = b * 256 + t;
    if (i < N_NODES) {
        int r = rowptr[i] + boff[b];
        rowptr[i] = r;
        cursor[i] = r;
    }
    if (i == 0) rowptr[N_NODES] = E_EDGES;
}

__global__ void k_fill(const int* __restrict__ src, const int* __restrict__ dst,
                       int* __restrict__ cursor, int* __restrict__ eidx) {
    int e = blockIdx.x * blockDim.x + threadIdx.x;
    if (e < E_EDGES) {
        int p = atomicAdd(&cursor[dst[e]], 1);
        eidx[p] = src[e];
    }
}

// ---------------- gathers ----------------

// mean[i, :] = (1/max(deg,1)) * sum_{j in N(i)} x[j, :]
// block 256 thr = 8 nodes x 32 lanes; each lane owns a float4 column group.
__global__ void k_gather128(const int* __restrict__ rowptr, const int* __restrict__ eidx,
                            const float* __restrict__ x, float* __restrict__ mean) {
    int t = threadIdx.x;
    int i = blockIdx.x * 8 + (t >> 5);
    int g = t & 31;
    if (i >= N_NODES) return;
    int beg = rowptr[i], end = rowptr[i + 1];
    float4 acc = make_float4(0.f, 0.f, 0.f, 0.f);
    int j = beg;
    for (; j + 3 < end; j += 4) {
        int s0 = eidx[j], s1 = eidx[j + 1], s2 = eidx[j + 2], s3 = eidx[j + 3];
        float4 v0 = *(const float4*)&x[(size_t)s0 * 128 + g * 4];
        float4 v1 = *(const float4*)&x[(size_t)s1 * 128 + g * 4];
        float4 v2 = *(const float4*)&x[(size_t)s2 * 128 + g * 4];
        float4 v3 = *(const float4*)&x[(size_t)s3 * 128 + g * 4];
        acc.x += v0.x + v1.x + v2.x + v3.x;
        acc.y += v0.y + v1.y + v2.y + v3.y;
        acc.z += v0.z + v1.z + v2.z + v3.z;
        acc.w += v0.w + v1.w + v2.w + v3.w;
    }
    for (; j < end; ++j) {
        float4 v = *(const float4*)&x[(size_t)eidx[j] * 128 + g * 4];
        acc.x += v.x; acc.y += v.y; acc.z += v.z; acc.w += v.w;
    }
    float inv = 1.0f / fmaxf((float)(end - beg), 1.0f);
    acc.x *= inv; acc.y *= inv; acc.z *= inv; acc.w *= inv;
    *(float4*)&mean[(size_t)i * 128 + g * 4] = acc;
}

// out[i,o] = z[i,80][40+o] + inv * sum_{j in N(i)} z[j,80][o]   (o < 40)
// block = 320 threads = 8 nodes x 40 lanes (grid*8 == N exactly)
__global__ void k_gather40(const int* __restrict__ rowptr, const int* __restrict__ eidx,
                           const float* __restrict__ z, float* __restrict__ out) {
    int t = threadIdx.x;
    int i = blockIdx.x * 8 + t / 40;
    int o = t % 40;
    int beg = rowptr[i], end = rowptr[i + 1];
    float acc = 0.0f;
    int j = beg;
    for (; j + 3 < end; j += 4) {
        int s0 = eidx[j], s1 = eidx[j + 1], s2 = eidx[j + 2], s3 = eidx[j + 3];
        float v0 = z[(size_t)s0 * 80 + o];
        float v1 = z[(size_t)s1 * 80 + o];
        float v2 = z[(size_t)s2 * 80 + o];
        float v3 = z[(size_t)s3 * 80 + o];
        acc += v0 + v1 + v2 + v3;
    }
    for (; j < end; ++j)
        acc += z[(size_t)eidx[j] * 80 + o];
    float inv = 1.0f / fmaxf((float)(end - beg), 1.0f);
    out[(size_t)i * 40 + o] = z[(size_t)i * 80 + 40 + o] + acc * inv;
}

// ---------------- layer 1 dense: LDS-staged A, scalar-B ----------------
// h[n,c] = relu( mean[n,:].W1l[c,:] + x[n,:].W1r[c,:] + b1[c] )
// block 256 thr: lane = node (64-node tile), wave wv -> 16 cols; cblk -> col half.
// A staged in As[64][65] (bank (lane+k)%32, conflict-free); B via uniform s_load.
__launch_bounds__(256)
__global__ void k_dense1(const float* __restrict__ mean, const float* __restrict__ x,
                         const float* __restrict__ W1l, const float* __restrict__ W1r,
                         const float* __restrict__ b1, float* __restrict__ h) {
    __shared__ float As[64][65];
    int t = threadIdx.x;
    int lane = t & 63;
    int nblk = blockIdx.x >> 1, cblk = blockIdx.x & 1;
    int wv = t >> 6;
    int c0 = __builtin_amdgcn_readfirstlane(cblk * 64 + wv * 16);
    int node0 = nblk * 64;
    int n = node0 + lane;

    float acc[16];
#pragma unroll
    for (int q = 0; q < 16; ++q) acc[q] = 0.0f;

    for (int kt = 0; kt < 4; ++kt) {
        const float* __restrict__ Asrc = (kt < 2) ? mean : x;
        const float* __restrict__ W    = (kt < 2) ? W1l  : W1r;
        int kbase = (kt & 1) * 64;     // within the 128-wide source row / W row

        __syncthreads();
#pragma unroll
        for (int p = 0; p < 4; ++p) {
            int idx = t + p * 256;                 // float4 index in 64x64 tile
            int row = idx >> 4, c4 = (idx & 15) * 4;
            int rn = min(node0 + row, N_NODES - 1);
            float4 v = *(const float4*)(Asrc + (size_t)rn * 128 + kbase + c4);
            As[row][c4 + 0] = v.x;
            As[row][c4 + 1] = v.y;
            As[row][c4 + 2] = v.z;
            As[row][c4 + 3] = v.w;
        }
        __syncthreads();

        const float* __restrict__ Wk = W + kbase;
#pragma unroll 2
        for (int k4 = 0; k4 < 16; ++k4) {
            float a0 = As[lane][k4 * 4 + 0];
            float a1 = As[lane][k4 * 4 + 1];
            float a2 = As[lane][k4 * 4 + 2];
            float a3 = As[lane][k4 * 4 + 3];
#pragma unroll
            for (int q = 0; q < 16; ++q) {
                float4 bv = *(const float4*)(Wk + (size_t)(c0 + q) * 128 + k4 * 4);
                acc[q] = fmaf(a0, bv.x, acc[q]);
                acc[q] = fmaf(a1, bv.y, acc[q]);
                acc[q] = fmaf(a2, bv.z, acc[q]);
                acc[q] = fmaf(a3, bv.w, acc[q]);
            }
        }
    }

    if (n < N_NODES) {
#pragma unroll
        for (int g = 0; g < 4; ++g) {
            float4 r;
            r.x = fmaxf(acc[g * 4 + 0] + b1[c0 + g * 4 + 0], 0.0f);
            r.y = fmaxf(acc[g * 4 + 1] + b1[c0 + g * 4 + 1], 0.0f);
            r.z = fmaxf(acc[g * 4 + 2] + b1[c0 + g * 4 + 2], 0.0f);
            r.w = fmaxf(acc[g * 4 + 3] + b1[c0 + g * 4 + 3], 0.0f);
            *(float4*)&h[(size_t)n * 128 + c0 + g * 4] = r;
        }
    }
}

// ---------------- layer 2 dense: LDS-staged A, scalar-B ----------------
// z[n, cblk*40 + r0 + q] = h[n,:].W[r0+q,:] (+ b2 on right half)
__launch_bounds__(256)
__global__ void k_dense2(const float* __restrict__ h,
                         const float* __restrict__ W2l, const float* __restrict__ W2r,
                         const float* __restrict__ b2, float* __restrict__ z) {
    __shared__ float As[64][65];
    int t = threadIdx.x;
    int lane = t & 63;
    int nblk = blockIdx.x >> 1, cblk = blockIdx.x & 1;
    int wv = t >> 6;
    int r0 = __builtin_amdgcn_readfirstlane(wv * 10);
    int node0 = nblk * 64;
    int n = node0 + lane;

    const float* __restrict__ W = cblk ? W2r : W2l;

    float acc[10];
#pragma unroll
    for (int q = 0; q < 10; ++q) acc[q] = 0.0f;

    for (int kt = 0; kt < 2; ++kt) {
        int kbase = kt * 64;

        __syncthreads();
#pragma unroll
        for (int p = 0; p < 4; ++p) {
            int idx = t + p * 256;
            int row = idx >> 4, c4 = (idx & 15) * 4;
            int rn = min(node0 + row, N_NODES - 1);
            float4 v = *(const float4*)(h + (size_t)rn * 128 + kbase + c4);
            As[row][c4 + 0] = v.x;
            As[row][c4 + 1] = v.y;
            As[row][c4 + 2] = v.z;
            As[row][c4 + 3] = v.w;
        }
        __syncthreads();

        const float* __restrict__ Wk = W + kbase;
#pragma unroll 2
        for (int k4 = 0; k4 < 16; ++k4) {
            float a0 = As[lane][k4 * 4 + 0];
            float a1 = As[lane][k4 * 4 + 1];
            float a2 = As[lane][k4 * 4 + 2];
            float a3 = As[lane][k4 * 4 + 3];
#pragma unroll
            for (int q = 0; q < 10; ++q) {
                float4 bv = *(const float4*)(Wk + (size_t)(r0 + q) * 128 + k4 * 4);
                acc[q] = fmaf(a0, bv.x, acc[q]);
                acc[q] = fmaf(a1, bv.y, acc[q]);
                acc[q] = fmaf(a2, bv.z, acc[q]);
                acc[q] = fmaf(a3, bv.w, acc[q]);
            }
        }
    }

    if (n < N_NODES) {
        size_t base = (size_t)n * 80 + cblk * 40 + r0;
#pragma unroll
        for (int qq = 0; qq < 5; ++qq) {
            float b0 = cblk ? b2[r0 + 2 * qq]     : 0.0f;
            float b1v = cblk ? b2[r0 + 2 * qq + 1] : 0.0f;
            float2 r;
            r.x = acc[2 * qq]     + b0;
            r.y = acc[2 * qq + 1] + b1v;
            *(float2*)&z[base + 2 * qq] = r;
        }
    }
}

// ---------------- launch ----------------

extern "C" void kernel_launch(void* const* d_in, const int* in_sizes, int n_in,
                              void* d_out, int out_size, void* d_ws, size_t ws_size,
                              hipStream_t stream) {
    const float* x   = (const float*)d_in[0];
    const int*   ei  = (const int*)d_in[1];      // [2, E] int32
    const float* W1l = (const float*)d_in[2];
    const float* b1  = (const float*)d_in[3];
    const float* W1r = (const float*)d_in[4];
    const float* W2l = (const float*)d_in[5];
    const float* b2  = (const float*)d_in[6];
    const float* W2r = (const float*)d_in[7];

    const int* src = ei;
    const int* dst = ei + E_EDGES;

    // ---- workspace carve (16B-aligned) ----
    char* base = (char*)d_ws;
    size_t off = 0;
    auto carve = [&](size_t bytes) {
        void* p = base + off;
        off += (bytes + 15) & ~(size_t)15;
        return p;
    };
    int*   cnt    = (int*)  carve((size_t)N_NODES * 4);
    int*   rowptr = (int*)  carve((size_t)(N_NODES + 1) * 4);
    int*   cursor = (int*)  carve((size_t)N_NODES * 4);
    int*   eidx   = (int*)  carve((size_t)E_EDGES * 4);
    int*   bsum   = (int*)  carve((size_t)256 * 4);
    int*   boff   = (int*)  carve((size_t)256 * 4);
    float* mean   = (float*)carve((size_t)N_NODES * 128 * 4);
    float* h      = (float*)carve((size_t)N_NODES * 128 * 4);
    float* z      = mean;   // mean dead after k_dense1; z is N*80 < N*128
    float* outp   = (float*)d_out;

    // ---- CSR build ----
    hipMemsetAsync(cnt, 0, (size_t)N_NODES * 4, stream);
    k_count<<<(E_EDGES + 255) / 256, 256, 0, stream>>>(dst, cnt);
    k_scan_part<<<SCAN_NBLK, 256, 0, stream>>>(cnt, rowptr, bsum);
    k_scan_bsum<<<1, 256, 0, stream>>>(bsum, boff);
    k_scan_add<<<SCAN_NBLK, 256, 0, stream>>>(rowptr, boff, cursor);
    k_fill<<<(E_EDGES + 255) / 256, 256, 0, stream>>>(src, dst, cursor, eidx);

    // ---- layer 1 ----
    k_gather128<<<(N_NODES + 7) / 8, 256, 0, stream>>>(rowptr, eidx, x, mean);
    {
        int nblocks = ((N_NODES + 63) / 64) * 2;   // 782 node-tiles x 2 col-halves
        k_dense1<<<nblocks, 256, 0, stream>>>(mean, x, W1l, W1r, b1, h);
    }

    // ---- layer 2 ----
    {
        int nblocks = ((N_NODES + 63) / 64) * 2;   // 782 node-tiles x 2 col-halves
        k_dense2<<<nblocks, 256, 0, stream>>>(h, W2l, W2r, b2, z);
    }
    k_gather40<<<(N_NODES + 7) / 8, 320, 0, stream>>>(rowptr, eidx, z, outp);
}

// Round 9
// 270.296 us; speedup vs baseline: 1.2925x; 1.1344x over previous
//
#include <hip/hip_runtime.h>

#define N_NODES 50000
#define E_EDGES 800000
#define SCAN_NBLK 196   // ceil(50000/256)

__device__ __forceinline__ unsigned short f2bf(float f) {
    unsigned u = __float_as_uint(f);
    u = (u + 0x7FFF + ((u >> 16) & 1)) >> 16;   // RNE
    return (unsigned short)u;
}
__device__ __forceinline__ float bf2f(unsigned short s) {
    return __uint_as_float(((unsigned)s) << 16);
}

// ---------------- CSR build ----------------

__global__ void k_count(const int* __restrict__ dst, int* __restrict__ cnt) {
    int e = blockIdx.x * blockDim.x + threadIdx.x;
    if (e < E_EDGES) atomicAdd(&cnt[dst[e]], 1);
}

__global__ void k_scan_part(const int* __restrict__ cnt, int* __restrict__ excl,
                            int* __restrict__ bsum) {
    __shared__ int sm[256];
    int b = blockIdx.x, t = threadIdx.x;
    int i = b * 256 + t;
    int v = (i < N_NODES) ? cnt[i] : 0;
    sm[t] = v;
    __syncthreads();
    for (int off = 1; off < 256; off <<= 1) {
        int u = (t >= off) ? sm[t - off] : 0;
        __syncthreads();
        sm[t] += u;
        __syncthreads();
    }
    if (i < N_NODES) excl[i] = sm[t] - v;
    if (t == 255) bsum[b] = sm[255];
}

__global__ void k_scan_bsum(const int* __restrict__ bsum, int* __restrict__ boff) {
    __shared__ int sm[256];
    int t = threadIdx.x;
    int v = (t < SCAN_NBLK) ? bsum[t] : 0;
    sm[t] = v;
    __syncthreads();
    for (int off = 1; off < 256; off <<= 1) {
        int u = (t >= off) ? sm[t - off] : 0;
        __syncthreads();
        sm[t] += u;
        __syncthreads();
    }
    if (t < SCAN_NBLK) boff[t] = sm[t] - v;
}

__global__ void k_scan_add(int* __restrict__ rowptr, const int* __restrict__ boff,
                           int* __restrict__ cursor) {
    int b = blockIdx.x, t = threadIdx.x;
    int i = b * 256 + t;
    if (i < N_NODES) {
        int r = rowptr[i] + boff[b];
        rowptr[i] = r;
        cursor[i] = r;
    }
    if (i == 0) rowptr[N_NODES] = E_EDGES;
}

__global__ void k_fill(const int* __restrict__ src, const int* __restrict__ dst,
                       int* __restrict__ cursor, int* __restrict__ eidx) {
    int e = blockIdx.x * blockDim.x + threadIdx.x;
    if (e < E_EDGES) {
        int p = atomicAdd(&cursor[dst[e]], 1);
        eidx[p] = src[e];
    }
}

// ---------------- weights / cast ----------------

// WT[k*ldd + col_off + o] = W[o*K + k]
__global__ void k_transpose(const float* __restrict__ W, float* __restrict__ WT,
                            int O, int K, int ldd, int col_off) {
    int idx = blockIdx.x * blockDim.x + threadIdx.x;
    if (idx < O * K) {
        int o = idx / K, k = idx - o * K;
        WT[k * ldd + col_off + o] = W[idx];
    }
}

// xb = bf16(x), vectorized
__global__ void k_cast(const float* __restrict__ x, unsigned short* __restrict__ xb) {
    int tid = blockIdx.x * blockDim.x + threadIdx.x;
    const int total4 = N_NODES * 32;       // float4 groups
    for (int i = tid; i < total4; i += gridDim.x * blockDim.x) {
        float4 v = ((const float4*)x)[i];
        ushort4 o;
        o.x = f2bf(v.x); o.y = f2bf(v.y); o.z = f2bf(v.z); o.w = f2bf(v.w);
        ((ushort4*)xb)[i] = o;
    }
}

// ---------------- gathers ----------------

// mean[i,:] = (1/max(deg,1)) * sum_j xb[j,:]  (bf16 reads, fp32 accumulate)
// block 256 thr = 8 nodes x 32 lanes; lane owns 4 features (ushort4 = 8B/edge/lane).
__global__ void k_gather128(const int* __restrict__ rowptr, const int* __restrict__ eidx,
                            const unsigned short* __restrict__ xb,
                            float* __restrict__ mean) {
    int t = threadIdx.x;
    int i = blockIdx.x * 8 + (t >> 5);
    int g = t & 31;
    if (i >= N_NODES) return;
    int beg = rowptr[i], end = rowptr[i + 1];
    float a0 = 0.f, a1 = 0.f, a2 = 0.f, a3 = 0.f;
    int j = beg;
    for (; j + 3 < end; j += 4) {
        int s0 = eidx[j], s1 = eidx[j + 1], s2 = eidx[j + 2], s3 = eidx[j + 3];
        ushort4 u0 = *(const ushort4*)&xb[(size_t)s0 * 128 + g * 4];
        ushort4 u1 = *(const ushort4*)&xb[(size_t)s1 * 128 + g * 4];
        ushort4 u2 = *(const ushort4*)&xb[(size_t)s2 * 128 + g * 4];
        ushort4 u3 = *(const ushort4*)&xb[(size_t)s3 * 128 + g * 4];
        a0 += bf2f(u0.x) + bf2f(u1.x) + bf2f(u2.x) + bf2f(u3.x);
        a1 += bf2f(u0.y) + bf2f(u1.y) + bf2f(u2.y) + bf2f(u3.y);
        a2 += bf2f(u0.z) + bf2f(u1.z) + bf2f(u2.z) + bf2f(u3.z);
        a3 += bf2f(u0.w) + bf2f(u1.w) + bf2f(u2.w) + bf2f(u3.w);
    }
    for (; j < end; ++j) {
        ushort4 u = *(const ushort4*)&xb[(size_t)eidx[j] * 128 + g * 4];
        a0 += bf2f(u.x); a1 += bf2f(u.y); a2 += bf2f(u.z); a3 += bf2f(u.w);
    }
    float inv = 1.0f / fmaxf((float)(end - beg), 1.0f);
    float4 r; r.x = a0 * inv; r.y = a1 * inv; r.z = a2 * inv; r.w = a3 * inv;
    *(float4*)&mean[(size_t)i * 128 + g * 4] = r;
}

// out[i,o] = z[i,80][40+o] + inv * sum_j z[j,80][o]  (o < 40)
// block 320 thr = 8 nodes x 40 lanes (grid*8 == N exactly)
__global__ void k_gather40(const int* __restrict__ rowptr, const int* __restrict__ eidx,
                           const float* __restrict__ z, float* __restrict__ out) {
    int t = threadIdx.x;
    int i = blockIdx.x * 8 + t / 40;
    int o = t % 40;
    int beg = rowptr[i], end = rowptr[i + 1];
    float acc = 0.0f;
    int j = beg;
    for (; j + 3 < end; j += 4) {
        int s0 = eidx[j], s1 = eidx[j + 1], s2 = eidx[j + 2], s3 = eidx[j + 3];
        acc += z[(size_t)s0 * 80 + o] + z[(size_t)s1 * 80 + o]
             + z[(size_t)s2 * 80 + o] + z[(size_t)s3 * 80 + o];
    }
    for (; j < end; ++j)
        acc += z[(size_t)eidx[j] * 80 + o];
    float inv = 1.0f / fmaxf((float)(end - beg), 1.0f);
    out[(size_t)i * 40 + o] = z[(size_t)i * 80 + 40 + o] + acc * inv;
}

// ---------------- layer 1 dense (LDS-B, J=4) ----------------
// h[M,128] = relu([mean|x][M,256] @ B1cat[256,128] + b1)
// BM=128, BN=64 (cblk halves) -> grid 782. 256 thr: og=t&7 -> cols {og*4..+3, 32+og*4..+3}
// (distinct banks, broadcast within og group = conflict-free), mg=t>>3 -> 4 nodes.
// Per kk: 32B LDS / 32 FMA = 1 B/FMA -> ~30 us LDS floor, FMA floor 21 us.
__launch_bounds__(256)
__global__ void k_dense1(const float* __restrict__ mean, const float* __restrict__ x,
                         const float* __restrict__ Bcat,  // [256][128]
                         const float* __restrict__ b1, float* __restrict__ h) {
    __shared__ float Bs[64][64];
    int t = threadIdx.x;
    int og = t & 7, mg = t >> 3;
    int og4 = og * 4;
    int nblk = blockIdx.x >> 1, cblk = blockIdx.x & 1;
    int node0 = nblk * 128;
    int cb = cblk * 64;

    int mr[4];
#pragma unroll
    for (int j = 0; j < 4; ++j)
        mr[j] = min(node0 + mg * 4 + j, N_NODES - 1);

    float acc[4][8];
#pragma unroll
    for (int j = 0; j < 4; ++j)
#pragma unroll
        for (int q = 0; q < 8; ++q) acc[j][q] = 0.0f;

    for (int kt = 0; kt < 4; ++kt) {
        const float* __restrict__ Asrc = (kt < 2) ? mean : x;
        int kbase = (kt & 1) * 64;

        __syncthreads();
#pragma unroll
        for (int p = 0; p < 4; ++p) {
            int idx = t + p * 256;                // float4 idx in 64x64 tile
            int row = idx >> 4, q4 = (idx & 15) * 4;
            *(float4*)&Bs[row][q4] =
                *(const float4*)&Bcat[(size_t)(kt * 64 + row) * 128 + cb + q4];
        }
        __syncthreads();

#pragma unroll 2
        for (int k4 = 0; k4 < 16; ++k4) {
            float4 av[4];
#pragma unroll
            for (int j = 0; j < 4; ++j)
                av[j] = *(const float4*)(Asrc + (size_t)mr[j] * 128 + kbase + k4 * 4);

#pragma unroll
            for (int u = 0; u < 4; ++u) {
                int kk = k4 * 4 + u;
                float4 bq0 = *(const float4*)&Bs[kk][og4];
                float4 bq1 = *(const float4*)&Bs[kk][32 + og4];
#pragma unroll
                for (int j = 0; j < 4; ++j) {
                    float a = (u == 0) ? av[j].x : (u == 1) ? av[j].y
                              : (u == 2) ? av[j].z : av[j].w;
                    acc[j][0] = fmaf(a, bq0.x, acc[j][0]);
                    acc[j][1] = fmaf(a, bq0.y, acc[j][1]);
                    acc[j][2] = fmaf(a, bq0.z, acc[j][2]);
                    acc[j][3] = fmaf(a, bq0.w, acc[j][3]);
                    acc[j][4] = fmaf(a, bq1.x, acc[j][4]);
                    acc[j][5] = fmaf(a, bq1.y, acc[j][5]);
                    acc[j][6] = fmaf(a, bq1.z, acc[j][6]);
                    acc[j][7] = fmaf(a, bq1.w, acc[j][7]);
                }
            }
        }
    }

    float bias[8];
#pragma unroll
    for (int q = 0; q < 4; ++q) bias[q] = b1[cb + og4 + q];
#pragma unroll
    for (int q = 0; q < 4; ++q) bias[4 + q] = b1[cb + 32 + og4 + q];

#pragma unroll
    for (int j = 0; j < 4; ++j) {
        int m = node0 + mg * 4 + j;
        if (m < N_NODES) {
            float4 r0, r1;
            r0.x = fmaxf(acc[j][0] + bias[0], 0.0f);
            r0.y = fmaxf(acc[j][1] + bias[1], 0.0f);
            r0.z = fmaxf(acc[j][2] + bias[2], 0.0f);
            r0.w = fmaxf(acc[j][3] + bias[3], 0.0f);
            r1.x = fmaxf(acc[j][4] + bias[4], 0.0f);
            r1.y = fmaxf(acc[j][5] + bias[5], 0.0f);
            r1.z = fmaxf(acc[j][6] + bias[6], 0.0f);
            r1.w = fmaxf(acc[j][7] + bias[7], 0.0f);
            *(float4*)&h[(size_t)m * 128 + cb + og4] = r0;
            *(float4*)&h[(size_t)m * 128 + cb + 32 + og4] = r1;
        }
    }
}

// ---------------- layer 2 dense (LDS-B, J=2) ----------------
// z[M,80] = h[M,128] @ B2cat[128,80] (+b2 on right half)
// BM=128, BN=40 (cblk halves) -> grid 782. og=t&3 (10 cols), mg=t>>2 (2 nodes).
__launch_bounds__(256)
__global__ void k_dense2(const float* __restrict__ h,
                         const float* __restrict__ Bcat,  // [128][80]
                         const float* __restrict__ b2, float* __restrict__ z) {
    __shared__ float Bs[128][40];
    int t = threadIdx.x;
    int og = t & 3, mg = t >> 2;
    int o0 = og * 10;
    int nblk = blockIdx.x >> 1, cblk = blockIdx.x & 1;
    int node0 = nblk * 128;
    int n0 = node0 + mg * 2;
    int mr0 = min(n0, N_NODES - 1);
    int mr1 = min(n0 + 1, N_NODES - 1);

#pragma unroll
    for (int p = 0; p < 5; ++p) {
        int idx = t + p * 256;                    // float4 idx in 128x40 tile
        int row = idx / 10, q4 = (idx - row * 10) * 4;
        *(float4*)&Bs[row][q4] =
            *(const float4*)&Bcat[(size_t)row * 80 + cblk * 40 + q4];
    }
    __syncthreads();

    float acc[2][10];
#pragma unroll
    for (int j = 0; j < 2; ++j)
#pragma unroll
        for (int q = 0; q < 10; ++q) acc[j][q] = 0.0f;

    const float* a0p = h + (size_t)mr0 * 128;
    const float* a1p = h + (size_t)mr1 * 128;

#pragma unroll 2
    for (int k4 = 0; k4 < 32; ++k4) {
        float4 av0 = *(const float4*)(a0p + k4 * 4);
        float4 av1 = *(const float4*)(a1p + k4 * 4);
#pragma unroll
        for (int u = 0; u < 4; ++u) {
            int kk = k4 * 4 + u;
            float bv[10];
#pragma unroll
            for (int q = 0; q < 5; ++q) {
                float2 b2v = *(const float2*)&Bs[kk][o0 + 2 * q];
                bv[2 * q] = b2v.x;
                bv[2 * q + 1] = b2v.y;
            }
            float e0 = (u == 0) ? av0.x : (u == 1) ? av0.y : (u == 2) ? av0.z : av0.w;
            float e1 = (u == 0) ? av1.x : (u == 1) ? av1.y : (u == 2) ? av1.z : av1.w;
#pragma unroll
            for (int q = 0; q < 10; ++q) {
                acc[0][q] = fmaf(e0, bv[q], acc[0][q]);
                acc[1][q] = fmaf(e1, bv[q], acc[1][q]);
            }
        }
    }

    float bias[10];
#pragma unroll
    for (int q = 0; q < 10; ++q)
        bias[q] = cblk ? b2[o0 + q] : 0.0f;

#pragma unroll
    for (int j = 0; j < 2; ++j) {
        int m = n0 + j;
        if (m < N_NODES) {
            size_t base = (size_t)m * 80 + cblk * 40 + o0;
#pragma unroll
            for (int q = 0; q < 5; ++q) {
                float2 r;
                r.x = acc[j][2 * q] + bias[2 * q];
                r.y = acc[j][2 * q + 1] + bias[2 * q + 1];
                *(float2*)&z[base + 2 * q] = r;
            }
        }
    }
}

// ---------------- launch ----------------

extern "C" void kernel_launch(void* const* d_in, const int* in_sizes, int n_in,
                              void* d_out, int out_size, void* d_ws, size_t ws_size,
                              hipStream_t stream) {
    const float* x   = (const float*)d_in[0];
    const int*   ei  = (const int*)d_in[1];      // [2, E] int32
    const float* W1l = (const float*)d_in[2];
    const float* b1  = (const float*)d_in[3];
    const float* W1r = (const float*)d_in[4];
    const float* W2l = (const float*)d_in[5];
    const float* b2  = (const float*)d_in[6];
    const float* W2r = (const float*)d_in[7];

    const int* src = ei;
    const int* dst = ei + E_EDGES;

    // ---- workspace carve (16B-aligned) ----
    char* base = (char*)d_ws;
    size_t off = 0;
    auto carve = [&](size_t bytes) {
        void* p = base + off;
        off += (bytes + 15) & ~(size_t)15;
        return p;
    };
    int*   cnt    = (int*)  carve((size_t)N_NODES * 4);
    int*   rowptr = (int*)  carve((size_t)(N_NODES + 1) * 4);
    int*   cursor = (int*)  carve((size_t)N_NODES * 4);
    int*   eidx   = (int*)  carve((size_t)E_EDGES * 4);
    int*   bsum   = (int*)  carve((size_t)256 * 4);
    int*   boff   = (int*)  carve((size_t)256 * 4);
    float* b1cat  = (float*)carve((size_t)256 * 128 * 4);            // [256][128]
    float* b2cat  = (float*)carve((size_t)128 * 80 * 4);             // [128][80]
    unsigned short* xb = (unsigned short*)carve((size_t)N_NODES * 128 * 2);
    float* mean   = (float*)carve((size_t)N_NODES * 128 * 4);
    float* h      = (float*)carve((size_t)N_NODES * 128 * 4);
    float* z      = mean;   // mean dead after k_dense1; z is N*80 < N*128
    float* outp   = (float*)d_out;

    // ---- CSR build ----
    hipMemsetAsync(cnt, 0, (size_t)N_NODES * 4, stream);
    k_count<<<(E_EDGES + 255) / 256, 256, 0, stream>>>(dst, cnt);
    k_scan_part<<<SCAN_NBLK, 256, 0, stream>>>(cnt, rowptr, bsum);
    k_scan_bsum<<<1, 256, 0, stream>>>(bsum, boff);
    k_scan_add<<<SCAN_NBLK, 256, 0, stream>>>(rowptr, boff, cursor);
    k_fill<<<(E_EDGES + 255) / 256, 256, 0, stream>>>(src, dst, cursor, eidx);

    // ---- weight prep + bf16 cast ----
    k_transpose<<<(16384 + 255) / 256, 256, 0, stream>>>(W1l, b1cat, 128, 128, 128, 0);
    k_transpose<<<(16384 + 255) / 256, 256, 0, stream>>>(W1r, b1cat + 128 * 128, 128, 128, 128, 0);
    k_transpose<<<(5120 + 255) / 256, 256, 0, stream>>>(W2l, b2cat, 40, 128, 80, 0);
    k_transpose<<<(5120 + 255) / 256, 256, 0, stream>>>(W2r, b2cat, 40, 128, 80, 40);
    k_cast<<<2048, 256, 0, stream>>>(x, xb);

    // ---- layer 1 ----
    k_gather128<<<(N_NODES + 7) / 8, 256, 0, stream>>>(rowptr, eidx, xb, mean);
    {
        int nblocks = ((N_NODES + 127) / 128) * 2;   // 391 node-tiles x 2 col-halves
        k_dense1<<<nblocks, 256, 0, stream>>>(mean, x, b1cat, b1, h);
    }

    // ---- layer 2 ----
    {
        int nblocks = ((N_NODES + 127) / 128) * 2;   // 391 node-tiles x 2 col-halves
        k_dense2<<<nblocks, 256, 0, stream>>>(h, b2cat, b2, z);
    }
    k_gather40<<<(N_NODES + 7) / 8, 320, 0, stream>>>(rowptr, eidx, z, outp);
}